// Round 10
// baseline (331.968 us; speedup 1.0000x reference)
//
#include <hip/hip_runtime.h>
#include <math.h>

typedef unsigned short ushort_t;
typedef unsigned int uint_t;

// Problem constants
#define B_      8
#define T_      2048
#define DIMX    512
#define DM      128
#define DINNER  256
#define NSTATE  16
#define HDIM    64
#define NH      4
#define CONVDIM 288
#define PROJ    548
#define KCONV   4
#define LLAYERS 2
#define QCH     128
#define NC      (T_/QCH)
#define EPSF    1e-5f
#define MTOK    (B_*T_)

// ---- workspace layout (float offsets) — identical to round-8 passing build ----
#define OFF_H      0u
#define OFF_PROJ   2097152u
#define OFF_HBC    11075584u
#define OFF_Y      15794176u
#define OFF_DTP    19988480u
#define OFF_CUM    20054016u
#define OFF_Z      20119552u
#define OFF_SPREV  20643840u
#define OFF_DEC    21168128u
#define OFF_PART   21168640u
#define OFF_BF     21299712u
#define OFF_WTIN   23396864u
#define OFF_WTINP  23429632u
#define OFF_WTOUT  23503360u

__device__ __forceinline__ ushort_t f2b(float f) {
    uint_t u = __builtin_bit_cast(uint_t, f);
    return (ushort_t)((u + 0x7FFFu + ((u >> 16) & 1u)) >> 16);
}
__device__ __forceinline__ float b2f(ushort_t b) {
    uint_t u = ((uint_t)b) << 16;
    return __builtin_bit_cast(float, u);
}

typedef short bf8 __attribute__((ext_vector_type(8)));
typedef float f4v __attribute__((ext_vector_type(4)));

// ===== all weight transposes in ONE kernel (proven r8) =====
__global__ __launch_bounds__(256) void k_wt_all(
    const float* __restrict__ in_w, const float* __restrict__ inproj_w,
    const float* __restrict__ outproj_w,
    ushort_t* __restrict__ wt_in, ushort_t* __restrict__ wt_inp,
    ushort_t* __restrict__ wt_out)
{
    __shared__ float tile[64][65];
    int idx = blockIdx.x;
    const float* W; ushort_t* Wt; int K, N, k0, n0;
    if (idx < 16) {
        W = in_w; Wt = wt_in; K = 512; N = 128;
        k0 = (idx & 7) * 64; n0 = (idx >> 3) * 64;
    } else if (idx < 52) {
        int r = idx - 16; int l = r / 18; r -= l * 18;
        W = inproj_w + l * 128 * PROJ; Wt = wt_inp + l * 576 * 128; K = 128; N = PROJ;
        k0 = (r & 1) * 64; n0 = (r >> 1) * 64;
    } else {
        int r = idx - 52; int l = r / 8; r -= l * 8;
        W = outproj_w + l * 256 * 128; Wt = wt_out + l * 128 * 256; K = 256; N = 128;
        k0 = (r & 3) * 64; n0 = (r >> 2) * 64;
    }
    const int tid = threadIdx.x;
#pragma unroll
    for (int it = 0; it < 16; ++it) {
        const int e = it * 256 + tid;
        const int kk = e >> 6, nn = e & 63;
        tile[kk][nn] = (n0 + nn < N) ? W[(k0 + kk) * N + (n0 + nn)] : 0.f;
    }
    __syncthreads();
#pragma unroll
    for (int it = 0; it < 16; ++it) {
        const int e = it * 256 + tid;
        const int nn = e >> 6, kk = e & 63;
        Wt[(n0 + nn) * K + k0 + kk] = f2b(tile[kk][nn]);
    }
}

// ===== MFMA GEMM template (proven r8) =====
// EPI: 0 = plain, 1 = +bias(aux[col]), 2 = += C in place (residual)
template<int KTOT, int LDC, int NGUARD, int EPI, bool ABF16>
__global__ __launch_bounds__(256) void k_gemm(
    const void* __restrict__ Ap, const ushort_t* __restrict__ Bt,
    const float* __restrict__ aux, float* __restrict__ C)
{
    __shared__ ushort_t Als[64 * 136];
    __shared__ ushort_t Bls[64 * 136];
    const int m0 = blockIdx.x * 64, n0 = blockIdx.y * 64;
    const int tid = threadIdx.x;
    const int lane = tid & 63, w = tid >> 6;
    const int wm = (w >> 1) * 32, wn = (w & 1) * 32;
    const int r16 = lane & 15, q8 = (lane >> 4) * 8;

    f4v acc[2][2];
#pragma unroll
    for (int i = 0; i < 2; ++i)
#pragma unroll
        for (int j = 0; j < 2; ++j) acc[i][j] = (f4v)0.f;

    for (int kc = 0; kc < KTOT; kc += 128) {
        if constexpr (ABF16) {
            const ushort_t* A = (const ushort_t*)Ap;
#pragma unroll
            for (int i = 0; i < 4; ++i) {
                const int e = i * 2048 + tid * 8;
                const int r = e >> 7, c = e & 127;
                *(uint4*)&Als[r * 136 + c] = *(const uint4*)&A[(m0 + r) * KTOT + kc + c];
            }
        } else {
            const float* A = (const float*)Ap;
#pragma unroll
            for (int i = 0; i < 4; ++i) {
                const int e = i * 2048 + tid * 8;
                const int r = e >> 7, c = e & 127;
                const float4 f0 = *(const float4*)&A[(m0 + r) * KTOT + kc + c];
                const float4 f1 = *(const float4*)&A[(m0 + r) * KTOT + kc + c + 4];
                uint4 pk;
                pk.x = (uint_t)f2b(f0.x) | ((uint_t)f2b(f0.y) << 16);
                pk.y = (uint_t)f2b(f0.z) | ((uint_t)f2b(f0.w) << 16);
                pk.z = (uint_t)f2b(f1.x) | ((uint_t)f2b(f1.y) << 16);
                pk.w = (uint_t)f2b(f1.z) | ((uint_t)f2b(f1.w) << 16);
                *(uint4*)&Als[r * 136 + c] = pk;
            }
        }
#pragma unroll
        for (int i = 0; i < 4; ++i) {
            const int e = i * 2048 + tid * 8;
            const int r = e >> 7, c = e & 127;
            *(uint4*)&Bls[r * 136 + c] = *(const uint4*)&Bt[(n0 + r) * KTOT + kc + c];
        }
        __syncthreads();
#pragma unroll
        for (int kk = 0; kk < 128; kk += 32) {
            const bf8 a0 = *(const bf8*)&Als[(wm + r16) * 136 + kk + q8];
            const bf8 a1 = *(const bf8*)&Als[(wm + 16 + r16) * 136 + kk + q8];
            const bf8 b0 = *(const bf8*)&Bls[(wn + r16) * 136 + kk + q8];
            const bf8 b1 = *(const bf8*)&Bls[(wn + 16 + r16) * 136 + kk + q8];
            acc[0][0] = __builtin_amdgcn_mfma_f32_16x16x32_bf16(a0, b0, acc[0][0], 0, 0, 0);
            acc[0][1] = __builtin_amdgcn_mfma_f32_16x16x32_bf16(a0, b1, acc[0][1], 0, 0, 0);
            acc[1][0] = __builtin_amdgcn_mfma_f32_16x16x32_bf16(a1, b0, acc[1][0], 0, 0, 0);
            acc[1][1] = __builtin_amdgcn_mfma_f32_16x16x32_bf16(a1, b1, acc[1][1], 0, 0, 0);
        }
        __syncthreads();
    }
    const int q4 = (lane >> 4) * 4;
#pragma unroll
    for (int i = 0; i < 2; ++i)
#pragma unroll
        for (int j = 0; j < 2; ++j)
#pragma unroll
            for (int r = 0; r < 4; ++r) {
                const int grow = m0 + wm + i * 16 + q4 + r;
                const int gcol = n0 + wn + j * 16 + r16;
                if (NGUARD == 0 || gcol < NGUARD) {
                    float v = acc[i][j][r];
                    if (EPI == 1) v += aux[gcol];
                    if (EPI == 2) v += C[grow * LDC + gcol];
                    C[grow * LDC + gcol] = v;
                }
            }
}

// ===== ONLY delta vs r8: fused rmsnorm + inproj GEMM -> fp32 proj (548 cols) =====
__global__ __launch_bounds__(256) void k_inproj(
    const float* __restrict__ h, const float* __restrict__ nw,
    const ushort_t* __restrict__ Wt, float* __restrict__ proj)
{
    __shared__ float hls[64 * 128];
    __shared__ float red[256];
    __shared__ float rstds[64];
    __shared__ ushort_t Als[64 * 136];
    __shared__ ushort_t Bls[64 * 136];
    const int m0 = blockIdx.x * 64, n0 = blockIdx.y * 64;
    const int tid = threadIdx.x;

    for (int e4 = tid; e4 < 2048; e4 += 256) {
        const int row = e4 >> 5, c4 = (e4 & 31) * 4;
        *(float4*)&hls[row * 128 + c4] = *(const float4*)&h[(m0 + row) * 128 + c4];
    }
    __syncthreads();
    {
        const int row = tid >> 2, seg = tid & 3;
        float s = 0.f;
#pragma unroll
        for (int i = 0; i < 32; ++i) { const float v = hls[row * 128 + seg * 32 + i]; s += v * v; }
        red[tid] = s;
    }
    __syncthreads();
    if (tid < 64)
        rstds[tid] = rsqrtf((red[tid * 4] + red[tid * 4 + 1] + red[tid * 4 + 2] + red[tid * 4 + 3]) * (1.f / 128.f) + EPSF);
    __syncthreads();
    for (int e4 = tid; e4 < 2048; e4 += 256) {
        const int row = e4 >> 5, c4 = (e4 & 31) * 4;
        const float4 v = *(const float4*)&hls[row * 128 + c4];
        const float4 wv = *(const float4*)&nw[c4];
        const float rs = rstds[row];
        uint2 pk;
        pk.x = (uint_t)f2b(v.x * rs * wv.x) | ((uint_t)f2b(v.y * rs * wv.y) << 16);
        pk.y = (uint_t)f2b(v.z * rs * wv.z) | ((uint_t)f2b(v.w * rs * wv.w) << 16);
        *(uint2*)&Als[row * 136 + c4] = pk;
    }
    for (int e = tid; e < 1024; e += 256) {
        const int r = e >> 4, c8 = (e & 15) * 8;
        *(uint4*)&Bls[r * 136 + c8] = *(const uint4*)&Wt[(n0 + r) * 128 + c8];
    }
    __syncthreads();

    const int lane = tid & 63, w = tid >> 6;
    const int wm = (w >> 1) * 32, wn = (w & 1) * 32;
    const int r16 = lane & 15, q8 = (lane >> 4) * 8, q4 = (lane >> 4) * 4;
    f4v acc[2][2];
#pragma unroll
    for (int i = 0; i < 2; ++i)
#pragma unroll
        for (int j = 0; j < 2; ++j) acc[i][j] = (f4v)0.f;
#pragma unroll
    for (int kk = 0; kk < 128; kk += 32) {
        const bf8 a0 = *(const bf8*)&Als[(wm + r16) * 136 + kk + q8];
        const bf8 a1 = *(const bf8*)&Als[(wm + 16 + r16) * 136 + kk + q8];
        const bf8 b0 = *(const bf8*)&Bls[(wn + r16) * 136 + kk + q8];
        const bf8 b1 = *(const bf8*)&Bls[(wn + 16 + r16) * 136 + kk + q8];
        acc[0][0] = __builtin_amdgcn_mfma_f32_16x16x32_bf16(a0, b0, acc[0][0], 0, 0, 0);
        acc[0][1] = __builtin_amdgcn_mfma_f32_16x16x32_bf16(a0, b1, acc[0][1], 0, 0, 0);
        acc[1][0] = __builtin_amdgcn_mfma_f32_16x16x32_bf16(a1, b0, acc[1][0], 0, 0, 0);
        acc[1][1] = __builtin_amdgcn_mfma_f32_16x16x32_bf16(a1, b1, acc[1][1], 0, 0, 0);
    }
#pragma unroll
    for (int i = 0; i < 2; ++i)
#pragma unroll
        for (int j = 0; j < 2; ++j)
#pragma unroll
            for (int r = 0; r < 4; ++r) {
                const int grow = m0 + wm + i * 16 + q4 + r;
                const int gcol = n0 + wn + j * 16 + r16;
                if (gcol < PROJ) proj[grow * PROJ + gcol] = acc[i][j][r];
            }
}

// ===== gated rmsnorm -> bf16 (proven r8, fp32 inputs) =====
__global__ __launch_bounds__(256) void k_gnorm(
    const float* __restrict__ y, const float* __restrict__ proj,
    const float* __restrict__ gw, ushort_t* __restrict__ vb)
{
    const int tok = blockIdx.x * 4 + (threadIdx.x >> 6);
    const int lane = threadIdx.x & 63;
    const float4 yv = *(const float4*)&y[tok * 256 + lane * 4];
    const float4 g = *(const float4*)&proj[tok * PROJ + lane * 4];
    float4 v;
    v.x = yv.x * (g.x / (1.f + __expf(-g.x)));
    v.y = yv.y * (g.y / (1.f + __expf(-g.y)));
    v.z = yv.z * (g.z / (1.f + __expf(-g.z)));
    v.w = yv.w * (g.w / (1.f + __expf(-g.w)));
    float s = v.x * v.x + v.y * v.y + v.z * v.z + v.w * v.w;
#pragma unroll
    for (int off = 32; off; off >>= 1) s += __shfl_xor(s, off);
    const float rs = rsqrtf(s * (1.f / 256.f) + EPSF);
    const float4 w4 = *(const float4*)&gw[lane * 4];
    uint2 pk;
    pk.x = (uint_t)f2b(v.x * rs * w4.x) | ((uint_t)f2b(v.y * rs * w4.y) << 16);
    pk.y = (uint_t)f2b(v.z * rs * w4.z) | ((uint_t)f2b(v.w * rs * w4.w) << 16);
    ((uint2*)vb)[tok * 64 + lane] = pk;
}

// ===== dt = softplus(raw + bias); per-chunk inclusive cumsum (proven r8) =====
__global__ __launch_bounds__(128) void k_dtprep(
    const float* __restrict__ proj, const float* __restrict__ A_log,
    const float* __restrict__ dt_bias, float* __restrict__ dtp,
    float* __restrict__ cum, int l)
{
    __shared__ float sc[128];
    const int bid = blockIdx.x;
    const int c = bid & (NC - 1);
    const int hh = (bid / NC) & (NH - 1);
    const int b = bid / (NC * NH);
    const int t = threadIdx.x;
    const int m = b * T_ + c * QCH + t;
    const float Ah = -expf(A_log[l * NH + hh]);
    const float raw = proj[m * PROJ + DINNER + CONVDIM + hh] + dt_bias[l * NH + hh];
    const float dtv = (raw > 20.f) ? raw : log1pf(expf(raw));
    sc[t] = dtv * Ah;
    __syncthreads();
    for (int off = 1; off < 128; off <<= 1) {
        const float v = (t >= off) ? sc[t - off] : 0.f;
        __syncthreads();
        sc[t] += v;
        __syncthreads();
    }
    dtp[m * NH + hh] = dtv;
    cum[m * NH + hh] = sc[t];
}

// ===== depthwise causal conv (K=4) + silu (proven r8) =====
__global__ __launch_bounds__(256) void k_conv(
    const float* __restrict__ proj, const float* __restrict__ cw,
    const float* __restrict__ cb, float* __restrict__ hbc, int l)
{
    const int e = blockIdx.x * 256 + threadIdx.x;
    if (e >= MTOK * CONVDIM) return;
    const int m = e / CONVDIM;
    const int cch = e - m * CONVDIM;
    const int b = m >> 11;
    const int t = m & (T_ - 1);
    const float* wp = cw + (l * CONVDIM + cch) * KCONV;
    float acc = cb[l * CONVDIM + cch];
#pragma unroll
    for (int k = 0; k < KCONV; ++k) {
        const int tt = t - (KCONV - 1) + k;
        if (tt >= 0) acc += proj[(b * T_ + tt) * PROJ + DINNER + cch] * wp[k];
    }
    hbc[m * CONVDIM + cch] = acc / (1.f + __expf(-acc));
}

// ===== SSD chunk state (proven r8) =====
__global__ __launch_bounds__(256) void k_ssd_state(
    const float* __restrict__ hbc, const float* __restrict__ dtp,
    const float* __restrict__ cum, float* __restrict__ zbuf,
    float* __restrict__ dec)
{
    __shared__ ushort_t Xt[64 * 136];
    __shared__ ushort_t wB[16 * 136];
    __shared__ float cumls[QCH];
    __shared__ float dtls[QCH];
    const int bid = blockIdx.x;
    const int c = bid & (NC - 1);
    const int hh = (bid / NC) & (NH - 1);
    const int b = bid / (NC * NH);
    const int m0 = b * T_ + c * QCH;
    const int tid = threadIdx.x;

    if (tid < QCH) {
        cumls[tid] = cum[(m0 + tid) * NH + hh];
        dtls[tid] = dtp[(m0 + tid) * NH + hh];
    }
    __syncthreads();
    const float clast = cumls[QCH - 1];
    {
        const int p = tid & 63;
        const int s0 = tid >> 6;
#pragma unroll
        for (int pass = 0; pass < 32; ++pass) {
            const int s = s0 + pass * 4;
            Xt[p * 136 + s] = f2b(hbc[(m0 + s) * CONVDIM + hh * 64 + p]);
        }
    }
    for (int e = tid; e < QCH * 16; e += 256) {
        const int n = e & 15, s = e >> 4;
        const float w = __expf(clast - cumls[s]) * dtls[s];
        wB[n * 136 + s] = f2b(w * hbc[(m0 + s) * CONVDIM + DINNER + n]);
    }
    __syncthreads();

    const int lane = tid & 63, w = tid >> 6;
    const int r16 = lane & 15, q8 = (lane >> 4) * 8, q4 = (lane >> 4) * 4;
    f4v acc = (f4v)0.f;
#pragma unroll
    for (int kc = 0; kc < 128; kc += 32) {
        const bf8 a = *(const bf8*)&Xt[(w * 16 + r16) * 136 + kc + q8];
        const bf8 bb = *(const bf8*)&wB[r16 * 136 + kc + q8];
        acc = __builtin_amdgcn_mfma_f32_16x16x32_bf16(a, bb, acc, 0, 0, 0);
    }
#pragma unroll
    for (int r = 0; r < 4; ++r) {
        const int p = w * 16 + q4 + r;
        zbuf[bid * 1024 + p * 16 + r16] = acc[r];
    }
    if (tid == 0) dec[bid] = __expf(clast);
}

// ===== inter-chunk state scan (proven r8) =====
__global__ __launch_bounds__(256) void k_state_scan(
    const float* __restrict__ zbuf, const float* __restrict__ dec,
    float* __restrict__ sprev)
{
    const int bh = blockIdx.x;
    const int tid = threadIdx.x;
    float4 S; S.x = 0.f; S.y = 0.f; S.z = 0.f; S.w = 0.f;
    for (int c = 0; c < NC; ++c) {
        const int idx = (bh * NC + c) * 1024 + tid * 4;
        *(float4*)(sprev + idx) = S;
        const float d = dec[bh * NC + c];
        const float4 z = *(const float4*)(zbuf + idx);
        S.x = S.x * d + z.x; S.y = S.y * d + z.y;
        S.z = S.z * d + z.z; S.w = S.w * d + z.w;
    }
}

// ===== fused SSD y (proven r8, fp32 ybuf) =====
__global__ __launch_bounds__(256) void k_ssd_y(
    const float* __restrict__ hbc, const float* __restrict__ dtp,
    const float* __restrict__ cum, const float* __restrict__ sprev,
    const float* __restrict__ Dvec, float* __restrict__ ybuf, int l)
{
    __shared__ ushort_t Xt[64 * 136];
    __shared__ ushort_t BlsT[128 * 40];
    __shared__ ushort_t ClsT[128 * 40];
    __shared__ ushort_t Gls[128 * 136];
    __shared__ ushort_t Spt[64 * 40];
    __shared__ float cumls[QCH];
    __shared__ float dtls[QCH];
    const int bid = blockIdx.x;
    const int c = bid & (NC - 1);
    const int hh = (bid / NC) & (NH - 1);
    const int b = bid / (NC * NH);
    const int m0 = b * T_ + c * QCH;
    const int tid = threadIdx.x;

    if (tid < QCH) {
        cumls[tid] = cum[(m0 + tid) * NH + hh];
        dtls[tid] = dtp[(m0 + tid) * NH + hh];
    }
    {
        const int p = tid & 63;
        const int s0 = tid >> 6;
#pragma unroll
        for (int pass = 0; pass < 32; ++pass) {
            const int s = s0 + pass * 4;
            Xt[p * 136 + s] = f2b(hbc[(m0 + s) * CONVDIM + hh * 64 + p]);
        }
    }
    for (int e = tid; e < QCH * 16; e += 256) {
        const int n = e & 15, s = e >> 4;
        BlsT[s * 40 + n] = f2b(hbc[(m0 + s) * CONVDIM + DINNER + n]);
        BlsT[s * 40 + 16 + n] = 0;
        ClsT[s * 40 + n] = f2b(hbc[(m0 + s) * CONVDIM + DINNER + NSTATE + n]);
        ClsT[s * 40 + 16 + n] = 0;
    }
    for (int e = tid; e < 1024; e += 256) {
        const int n = e & 15, p = e >> 4;
        Spt[p * 40 + n] = f2b(sprev[bid * 1024 + p * 16 + n]);
        Spt[p * 40 + 16 + n] = 0;
    }
    __syncthreads();

    const int lane = tid & 63, w = tid >> 6;
    const int wrow = w * 32;
    const int r16 = lane & 15, q8 = (lane >> 4) * 8, q4 = (lane >> 4) * 4;
    const float Dh = Dvec[l * NH + hh];

    bf8 cfr[2];
#pragma unroll
    for (int i = 0; i < 2; ++i)
        cfr[i] = *(const bf8*)&ClsT[(wrow + i * 16 + r16) * 40 + q8];

    float cumt[8], et[8];
#pragma unroll
    for (int i = 0; i < 2; ++i)
#pragma unroll
        for (int r = 0; r < 4; ++r) {
            const int t = wrow + i * 16 + q4 + r;
            cumt[i * 4 + r] = cumls[t];
            et[i * 4 + r] = __expf(cumls[t]);
        }

    f4v acc[2][4];
#pragma unroll
    for (int j = 0; j < 4; ++j) {
        const bf8 sf = *(const bf8*)&Spt[(j * 16 + r16) * 40 + q8];
#pragma unroll
        for (int i = 0; i < 2; ++i) {
            f4v z = (f4v)0.f;
            z = __builtin_amdgcn_mfma_f32_16x16x32_bf16(cfr[i], sf, z, 0, 0, 0);
#pragma unroll
            for (int r = 0; r < 4; ++r) {
                const int t = wrow + i * 16 + q4 + r;
                const int p = j * 16 + r16;
                acc[i][j][r] = z[r] * et[i * 4 + r] + Dh * b2f(Xt[p * 136 + t]);
            }
        }
    }

#pragma unroll
    for (int ts = 0; ts < 8; ++ts) {
        const bf8 bf = *(const bf8*)&BlsT[(ts * 16 + r16) * 40 + q8];
        const int s = ts * 16 + r16;
        const float cs = cumls[s];
        const float ds = dtls[s];
#pragma unroll
        for (int i = 0; i < 2; ++i) {
            f4v g = (f4v)0.f;
            g = __builtin_amdgcn_mfma_f32_16x16x32_bf16(cfr[i], bf, g, 0, 0, 0);
#pragma unroll
            for (int r = 0; r < 4; ++r) {
                const int t = wrow + i * 16 + q4 + r;
                const float val = (s <= t) ? __expf(cumt[i * 4 + r] - cs) * ds * g[r] : 0.f;
                Gls[t * 136 + s] = f2b(val);
            }
        }
    }
    __syncthreads();

#pragma unroll
    for (int kc = 0; kc < 128; kc += 32) {
        bf8 af[2];
#pragma unroll
        for (int i = 0; i < 2; ++i)
            af[i] = *(const bf8*)&Gls[(wrow + i * 16 + r16) * 136 + kc + q8];
#pragma unroll
        for (int j = 0; j < 4; ++j) {
            const bf8 xf = *(const bf8*)&Xt[(j * 16 + r16) * 136 + kc + q8];
#pragma unroll
            for (int i = 0; i < 2; ++i)
                acc[i][j] = __builtin_amdgcn_mfma_f32_16x16x32_bf16(af[i], xf, acc[i][j], 0, 0, 0);
        }
    }

#pragma unroll
    for (int i = 0; i < 2; ++i)
#pragma unroll
        for (int r = 0; r < 4; ++r) {
            const int t = wrow + i * 16 + q4 + r;
#pragma unroll
            for (int j = 0; j < 4; ++j) {
                const int p = j * 16 + r16;
                ybuf[(m0 + t) * DINNER + hh * 64 + p] = acc[i][j][r];
            }
        }
}

// ===== final rmsnorm + partial mean-pool (proven) =====
__global__ __launch_bounds__(256) void k_finalnorm_pool(
    const float* __restrict__ h, const float* __restrict__ nfw,
    float* __restrict__ part)
{
    __shared__ float ht[2048];
    __shared__ float red[256];
    __shared__ float rstd[16];
    __shared__ float padd[256];
    const int tile = blockIdx.x & 127;
    const int b = blockIdx.x >> 7;
    const int m0 = b * T_ + tile * 16;
    const int tid = threadIdx.x;
    for (int e = tid; e < 2048; e += 256) ht[e] = h[m0 * DM + e];
    __syncthreads();
    {
        const int tg = tid >> 4, j0 = tid & 15;
        float p = 0.f;
#pragma unroll
        for (int k = 0; k < 8; ++k) { const float v = ht[tg * 128 + j0 + 16 * k]; p += v * v; }
        red[tid] = p;
    }
    __syncthreads();
    if (tid < 16) {
        float s = 0.f;
#pragma unroll
        for (int q = 0; q < 16; ++q) s += red[tid * 16 + q];
        rstd[tid] = rsqrtf(s * (1.f / 128.f) + EPSF);
    }
    __syncthreads();
    const int d = tid & 127, half = tid >> 7;
    float ps = 0.f;
#pragma unroll
    for (int i0 = 0; i0 < 8; ++i0) { const int i = half + 2 * i0; ps += ht[i * 128 + d] * rstd[i]; }
    padd[tid] = ps;
    __syncthreads();
    if (tid < 128) part[(b * 128 + tile) * 128 + tid] = (padd[tid] + padd[128 + tid]) * nfw[tid];
}

// ===== pooled reduce + head GEMM (proven) =====
__global__ __launch_bounds__(256) void k_head(
    const float* __restrict__ part, const float* __restrict__ ow,
    const float* __restrict__ ob, float* __restrict__ out)
{
    __shared__ float pooled[128];
    const int b = blockIdx.x;
    const int tid = threadIdx.x;
    if (tid < 128) {
        float s = 0.f;
        for (int tile = 0; tile < 128; ++tile) s += part[(b * 128 + tile) * 128 + tid];
        pooled[tid] = s * (1.f / (float)T_);
    }
    __syncthreads();
    for (int o = tid; o < DIMX; o += 256) {
        float acc = ob[o];
#pragma unroll 4
        for (int d = 0; d < 128; ++d) acc += pooled[d] * ow[d * DIMX + o];
        out[b * DIMX + o] = acc;
    }
}

extern "C" void kernel_launch(void* const* d_in, const int* in_sizes, int n_in,
                              void* d_out, int out_size, void* d_ws, size_t ws_size,
                              hipStream_t stream)
{
    const float* x         = (const float*)d_in[0];
    const float* in_w      = (const float*)d_in[1];
    const float* in_b      = (const float*)d_in[2];
    const float* norm_w    = (const float*)d_in[3];
    const float* inproj_w  = (const float*)d_in[4];
    const float* conv_w    = (const float*)d_in[5];
    const float* conv_b    = (const float*)d_in[6];
    const float* A_log     = (const float*)d_in[7];
    const float* Dvec      = (const float*)d_in[8];
    const float* dt_bias   = (const float*)d_in[9];
    const float* gnorm_w   = (const float*)d_in[10];
    const float* outproj_w = (const float*)d_in[11];
    const float* normf_w   = (const float*)d_in[12];
    const float* out_w     = (const float*)d_in[13];
    const float* out_b     = (const float*)d_in[14];

    float* ws    = (float*)d_ws;
    float* h     = ws + OFF_H;
    float* proj  = ws + OFF_PROJ;
    float* hbc   = ws + OFF_HBC;
    float* ybuf  = ws + OFF_Y;
    float* dtp   = ws + OFF_DTP;
    float* cumb  = ws + OFF_CUM;
    float* zbuf  = ws + OFF_Z;
    float* sprev = ws + OFF_SPREV;
    float* dec   = ws + OFF_DEC;
    float* part  = ws + OFF_PART;
    ushort_t* bf_scr = (ushort_t*)(ws + OFF_BF);
    ushort_t* wt_in  = (ushort_t*)(ws + OFF_WTIN);
    ushort_t* wt_inp = (ushort_t*)(ws + OFF_WTINP);
    ushort_t* wt_out = (ushort_t*)(ws + OFF_WTOUT);

    k_wt_all<<<68, 256, 0, stream>>>(in_w, inproj_w, outproj_w, wt_in, wt_inp, wt_out);

    k_gemm<512, 128, 0, 1, false><<<dim3(MTOK / 64, 2), 256, 0, stream>>>(x, wt_in, in_b, h);

    for (int l = 0; l < LLAYERS; ++l) {
        k_inproj<<<dim3(MTOK / 64, 9), 256, 0, stream>>>(
            h, norm_w + l * DM, wt_inp + l * 576 * 128, proj);
        k_dtprep<<<B_ * NH * NC, 128, 0, stream>>>(proj, A_log, dt_bias, dtp, cumb, l);
        k_conv<<<(MTOK * CONVDIM) / 256, 256, 0, stream>>>(proj, conv_w, conv_b, hbc, l);
        k_ssd_state<<<B_ * NH * NC, 256, 0, stream>>>(hbc, dtp, cumb, zbuf, dec);
        k_state_scan<<<B_ * NH, 256, 0, stream>>>(zbuf, dec, sprev);
        k_ssd_y<<<B_ * NH * NC, 256, 0, stream>>>(hbc, dtp, cumb, sprev, Dvec, ybuf, l);
        k_gnorm<<<MTOK / 4, 256, 0, stream>>>(ybuf, proj, gnorm_w + l * DINNER, bf_scr);
        k_gemm<256, 128, 0, 2, true><<<dim3(MTOK / 64, 2), 256, 0, stream>>>(
            bf_scr, wt_out + l * 128 * 256, nullptr, h);
    }

    k_finalnorm_pool<<<B_ * (T_ / 16), 256, 0, stream>>>(h, normf_w, part);
    k_head<<<B_, 256, 0, stream>>>(part, out_w, out_b, (float*)d_out);
}

// Round 11
// 303.647 us; speedup vs baseline: 1.0933x; 1.0933x over previous
//
#include <hip/hip_runtime.h>
#include <math.h>

typedef unsigned short ushort_t;
typedef unsigned int uint_t;

// Problem constants
#define B_      8
#define T_      2048
#define DIMX    512
#define DM      128
#define DINNER  256
#define NSTATE  16
#define HDIM    64
#define NH      4
#define CONVDIM 288
#define PROJ    548
#define KCONV   4
#define LLAYERS 2
#define QCH     128
#define NC      (T_/QCH)
#define EPSF    1e-5f
#define MTOK    (B_*T_)

// ---- workspace layout (float offsets) — identical to round-8 passing build ----
#define OFF_H      0u
#define OFF_PROJ   2097152u
#define OFF_HBC    11075584u
#define OFF_Y      15794176u
#define OFF_DTP    19988480u
#define OFF_CUM    20054016u
#define OFF_Z      20119552u
#define OFF_SPREV  20643840u
#define OFF_DEC    21168128u
#define OFF_PART   21168640u
#define OFF_BF     21299712u
#define OFF_WTIN   23396864u
#define OFF_WTINP  23429632u
#define OFF_WTOUT  23503360u

__device__ __forceinline__ ushort_t f2b(float f) {
    uint_t u = __builtin_bit_cast(uint_t, f);
    return (ushort_t)((u + 0x7FFFu + ((u >> 16) & 1u)) >> 16);
}
__device__ __forceinline__ float b2f(ushort_t b) {
    uint_t u = ((uint_t)b) << 16;
    return __builtin_bit_cast(float, u);
}

typedef short bf8 __attribute__((ext_vector_type(8)));
typedef float f4v __attribute__((ext_vector_type(4)));

// ===== all weight transposes in ONE kernel (proven r8) =====
__global__ __launch_bounds__(256) void k_wt_all(
    const float* __restrict__ in_w, const float* __restrict__ inproj_w,
    const float* __restrict__ outproj_w,
    ushort_t* __restrict__ wt_in, ushort_t* __restrict__ wt_inp,
    ushort_t* __restrict__ wt_out)
{
    __shared__ float tile[64][65];
    int idx = blockIdx.x;
    const float* W; ushort_t* Wt; int K, N, k0, n0;
    if (idx < 16) {
        W = in_w; Wt = wt_in; K = 512; N = 128;
        k0 = (idx & 7) * 64; n0 = (idx >> 3) * 64;
    } else if (idx < 52) {
        int r = idx - 16; int l = r / 18; r -= l * 18;
        W = inproj_w + l * 128 * PROJ; Wt = wt_inp + l * 576 * 128; K = 128; N = PROJ;
        k0 = (r & 1) * 64; n0 = (r >> 1) * 64;
    } else {
        int r = idx - 52; int l = r / 8; r -= l * 8;
        W = outproj_w + l * 256 * 128; Wt = wt_out + l * 128 * 256; K = 256; N = 128;
        k0 = (r & 3) * 64; n0 = (r >> 2) * 64;
    }
    const int tid = threadIdx.x;
#pragma unroll
    for (int it = 0; it < 16; ++it) {
        const int e = it * 256 + tid;
        const int kk = e >> 6, nn = e & 63;
        tile[kk][nn] = (n0 + nn < N) ? W[(k0 + kk) * N + (n0 + nn)] : 0.f;
    }
    __syncthreads();
#pragma unroll
    for (int it = 0; it < 16; ++it) {
        const int e = it * 256 + tid;
        const int nn = e >> 6, kk = e & 63;
        Wt[(n0 + nn) * K + k0 + kk] = f2b(tile[kk][nn]);
    }
}

// ===== MFMA GEMM template (proven r8) =====
// EPI: 0 = plain, 1 = +bias(aux[col]), 2 = += C in place (residual)
template<int KTOT, int LDC, int NGUARD, int EPI, bool ABF16>
__global__ __launch_bounds__(256) void k_gemm(
    const void* __restrict__ Ap, const ushort_t* __restrict__ Bt,
    const float* __restrict__ aux, float* __restrict__ C)
{
    __shared__ ushort_t Als[64 * 136];
    __shared__ ushort_t Bls[64 * 136];
    const int m0 = blockIdx.x * 64, n0 = blockIdx.y * 64;
    const int tid = threadIdx.x;
    const int lane = tid & 63, w = tid >> 6;
    const int wm = (w >> 1) * 32, wn = (w & 1) * 32;
    const int r16 = lane & 15, q8 = (lane >> 4) * 8;

    f4v acc[2][2];
#pragma unroll
    for (int i = 0; i < 2; ++i)
#pragma unroll
        for (int j = 0; j < 2; ++j) acc[i][j] = (f4v)0.f;

    for (int kc = 0; kc < KTOT; kc += 128) {
        if constexpr (ABF16) {
            const ushort_t* A = (const ushort_t*)Ap;
#pragma unroll
            for (int i = 0; i < 4; ++i) {
                const int e = i * 2048 + tid * 8;
                const int r = e >> 7, c = e & 127;
                *(uint4*)&Als[r * 136 + c] = *(const uint4*)&A[(m0 + r) * KTOT + kc + c];
            }
        } else {
            const float* A = (const float*)Ap;
#pragma unroll
            for (int i = 0; i < 4; ++i) {
                const int e = i * 2048 + tid * 8;
                const int r = e >> 7, c = e & 127;
                const float4 f0 = *(const float4*)&A[(m0 + r) * KTOT + kc + c];
                const float4 f1 = *(const float4*)&A[(m0 + r) * KTOT + kc + c + 4];
                uint4 pk;
                pk.x = (uint_t)f2b(f0.x) | ((uint_t)f2b(f0.y) << 16);
                pk.y = (uint_t)f2b(f0.z) | ((uint_t)f2b(f0.w) << 16);
                pk.z = (uint_t)f2b(f1.x) | ((uint_t)f2b(f1.y) << 16);
                pk.w = (uint_t)f2b(f1.z) | ((uint_t)f2b(f1.w) << 16);
                *(uint4*)&Als[r * 136 + c] = pk;
            }
        }
#pragma unroll
        for (int i = 0; i < 4; ++i) {
            const int e = i * 2048 + tid * 8;
            const int r = e >> 7, c = e & 127;
            *(uint4*)&Bls[r * 136 + c] = *(const uint4*)&Bt[(n0 + r) * KTOT + kc + c];
        }
        __syncthreads();
#pragma unroll
        for (int kk = 0; kk < 128; kk += 32) {
            const bf8 a0 = *(const bf8*)&Als[(wm + r16) * 136 + kk + q8];
            const bf8 a1 = *(const bf8*)&Als[(wm + 16 + r16) * 136 + kk + q8];
            const bf8 b0 = *(const bf8*)&Bls[(wn + r16) * 136 + kk + q8];
            const bf8 b1 = *(const bf8*)&Bls[(wn + 16 + r16) * 136 + kk + q8];
            acc[0][0] = __builtin_amdgcn_mfma_f32_16x16x32_bf16(a0, b0, acc[0][0], 0, 0, 0);
            acc[0][1] = __builtin_amdgcn_mfma_f32_16x16x32_bf16(a0, b1, acc[0][1], 0, 0, 0);
            acc[1][0] = __builtin_amdgcn_mfma_f32_16x16x32_bf16(a1, b0, acc[1][0], 0, 0, 0);
            acc[1][1] = __builtin_amdgcn_mfma_f32_16x16x32_bf16(a1, b1, acc[1][1], 0, 0, 0);
        }
        __syncthreads();
    }
    const int q4 = (lane >> 4) * 4;
#pragma unroll
    for (int i = 0; i < 2; ++i)
#pragma unroll
        for (int j = 0; j < 2; ++j)
#pragma unroll
            for (int r = 0; r < 4; ++r) {
                const int grow = m0 + wm + i * 16 + q4 + r;
                const int gcol = n0 + wn + j * 16 + r16;
                if (NGUARD == 0 || gcol < NGUARD) {
                    float v = acc[i][j][r];
                    if (EPI == 1) v += aux[gcol];
                    if (EPI == 2) v += C[grow * LDC + gcol];
                    C[grow * LDC + gcol] = v;
                }
            }
}

// ===== rmsnorm: h (fp32) -> hn (bf16) (proven r8) =====
__global__ __launch_bounds__(256) void k_rmsnorm(
    const float* __restrict__ h, const float* __restrict__ nw,
    ushort_t* __restrict__ hnb)
{
    const int tk = blockIdx.x * 4 + (threadIdx.x >> 6);
    const int lane = threadIdx.x & 63;
    const float2 v = *(const float2*)&h[tk * 128 + lane * 2];
    float s = v.x * v.x + v.y * v.y;
#pragma unroll
    for (int off = 32; off; off >>= 1) s += __shfl_xor(s, off);
    const float rs = rsqrtf(s * (1.f / 128.f) + EPSF);
    const float a = v.x * rs * nw[lane * 2];
    const float b = v.y * rs * nw[lane * 2 + 1];
    ((uint_t*)hnb)[tk * 64 + lane] = (uint_t)f2b(a) | ((uint_t)f2b(b) << 16);
}

// ===== gated rmsnorm -> bf16 (proven r8, fp32 inputs) =====
__global__ __launch_bounds__(256) void k_gnorm(
    const float* __restrict__ y, const float* __restrict__ proj,
    const float* __restrict__ gw, ushort_t* __restrict__ vb)
{
    const int tok = blockIdx.x * 4 + (threadIdx.x >> 6);
    const int lane = threadIdx.x & 63;
    const float4 yv = *(const float4*)&y[tok * 256 + lane * 4];
    const float4 g = *(const float4*)&proj[tok * PROJ + lane * 4];
    float4 v;
    v.x = yv.x * (g.x / (1.f + __expf(-g.x)));
    v.y = yv.y * (g.y / (1.f + __expf(-g.y)));
    v.z = yv.z * (g.z / (1.f + __expf(-g.z)));
    v.w = yv.w * (g.w / (1.f + __expf(-g.w)));
    float s = v.x * v.x + v.y * v.y + v.z * v.z + v.w * v.w;
#pragma unroll
    for (int off = 32; off; off >>= 1) s += __shfl_xor(s, off);
    const float rs = rsqrtf(s * (1.f / 256.f) + EPSF);
    const float4 w4 = *(const float4*)&gw[lane * 4];
    uint2 pk;
    pk.x = (uint_t)f2b(v.x * rs * w4.x) | ((uint_t)f2b(v.y * rs * w4.y) << 16);
    pk.y = (uint_t)f2b(v.z * rs * w4.z) | ((uint_t)f2b(v.w * rs * w4.w) << 16);
    ((uint2*)vb)[tok * 64 + lane] = pk;
}

// ===== ONLY delta vs r8: conv + dtprep merged into one launch (blockIdx split).
// Both branches are byte-identical math to r8's k_conv / k_dtprep; the branch
// is uniform per block so the barriers in the dtprep path are safe (k_wt_all
// pattern, proven).
__global__ __launch_bounds__(256) void k_convdt(
    const float* __restrict__ proj, const float* __restrict__ cw,
    const float* __restrict__ cb, const float* __restrict__ A_log,
    const float* __restrict__ dt_bias, float* __restrict__ hbc,
    float* __restrict__ dtp, float* __restrict__ cum, int l)
{
    __shared__ float sc[128];
    const int bid = blockIdx.x;
    const int tid = threadIdx.x;
    if (bid < (MTOK * CONVDIM) / 256) {
        // ---- conv (r8-exact) ----
        const int e = bid * 256 + tid;
        const int m = e / CONVDIM;
        const int cch = e - m * CONVDIM;
        const int b = m >> 11;
        const int t = m & (T_ - 1);
        const float* wp = cw + (l * CONVDIM + cch) * KCONV;
        float acc = cb[l * CONVDIM + cch];
#pragma unroll
        for (int k = 0; k < KCONV; ++k) {
            const int tt = t - (KCONV - 1) + k;
            if (tt >= 0) acc += proj[(b * T_ + tt) * PROJ + DINNER + cch] * wp[k];
        }
        hbc[m * CONVDIM + cch] = acc / (1.f + __expf(-acc));
    } else {
        // ---- dtprep (r8-exact, threads 128..255 idle but join barriers) ----
        const int bid2 = bid - (MTOK * CONVDIM) / 256;
        const int c = bid2 & (NC - 1);
        const int hh = (bid2 / NC) & (NH - 1);
        const int b = bid2 / (NC * NH);
        const int t = tid;
        float dtv = 0.f;
        if (t < 128) {
            const int m = b * T_ + c * QCH + t;
            const float Ah = -expf(A_log[l * NH + hh]);
            const float raw = proj[m * PROJ + DINNER + CONVDIM + hh] + dt_bias[l * NH + hh];
            dtv = (raw > 20.f) ? raw : log1pf(expf(raw));
            sc[t] = dtv * Ah;
        }
        __syncthreads();
        for (int off = 1; off < 128; off <<= 1) {
            const float v = (t >= off && t < 128) ? sc[t - off] : 0.f;
            __syncthreads();
            if (t < 128) sc[t] += v;
            __syncthreads();
        }
        if (t < 128) {
            const int m = b * T_ + c * QCH + t;
            dtp[m * NH + hh] = dtv;
            cum[m * NH + hh] = sc[t];
        }
    }
}

// ===== SSD chunk state (proven r8) =====
__global__ __launch_bounds__(256) void k_ssd_state(
    const float* __restrict__ hbc, const float* __restrict__ dtp,
    const float* __restrict__ cum, float* __restrict__ zbuf,
    float* __restrict__ dec)
{
    __shared__ ushort_t Xt[64 * 136];
    __shared__ ushort_t wB[16 * 136];
    __shared__ float cumls[QCH];
    __shared__ float dtls[QCH];
    const int bid = blockIdx.x;
    const int c = bid & (NC - 1);
    const int hh = (bid / NC) & (NH - 1);
    const int b = bid / (NC * NH);
    const int m0 = b * T_ + c * QCH;
    const int tid = threadIdx.x;

    if (tid < QCH) {
        cumls[tid] = cum[(m0 + tid) * NH + hh];
        dtls[tid] = dtp[(m0 + tid) * NH + hh];
    }
    __syncthreads();
    const float clast = cumls[QCH - 1];
    {
        const int p = tid & 63;
        const int s0 = tid >> 6;
#pragma unroll
        for (int pass = 0; pass < 32; ++pass) {
            const int s = s0 + pass * 4;
            Xt[p * 136 + s] = f2b(hbc[(m0 + s) * CONVDIM + hh * 64 + p]);
        }
    }
    for (int e = tid; e < QCH * 16; e += 256) {
        const int n = e & 15, s = e >> 4;
        const float w = __expf(clast - cumls[s]) * dtls[s];
        wB[n * 136 + s] = f2b(w * hbc[(m0 + s) * CONVDIM + DINNER + n]);
    }
    __syncthreads();

    const int lane = tid & 63, w = tid >> 6;
    const int r16 = lane & 15, q8 = (lane >> 4) * 8, q4 = (lane >> 4) * 4;
    f4v acc = (f4v)0.f;
#pragma unroll
    for (int kc = 0; kc < 128; kc += 32) {
        const bf8 a = *(const bf8*)&Xt[(w * 16 + r16) * 136 + kc + q8];
        const bf8 bb = *(const bf8*)&wB[r16 * 136 + kc + q8];
        acc = __builtin_amdgcn_mfma_f32_16x16x32_bf16(a, bb, acc, 0, 0, 0);
    }
#pragma unroll
    for (int r = 0; r < 4; ++r) {
        const int p = w * 16 + q4 + r;
        zbuf[bid * 1024 + p * 16 + r16] = acc[r];
    }
    if (tid == 0) dec[bid] = __expf(clast);
}

// ===== inter-chunk state scan (proven r8) =====
__global__ __launch_bounds__(256) void k_state_scan(
    const float* __restrict__ zbuf, const float* __restrict__ dec,
    float* __restrict__ sprev)
{
    const int bh = blockIdx.x;
    const int tid = threadIdx.x;
    float4 S; S.x = 0.f; S.y = 0.f; S.z = 0.f; S.w = 0.f;
    for (int c = 0; c < NC; ++c) {
        const int idx = (bh * NC + c) * 1024 + tid * 4;
        *(float4*)(sprev + idx) = S;
        const float d = dec[bh * NC + c];
        const float4 z = *(const float4*)(zbuf + idx);
        S.x = S.x * d + z.x; S.y = S.y * d + z.y;
        S.z = S.z * d + z.z; S.w = S.w * d + z.w;
    }
}

// ===== fused SSD y (proven r8, fp32 ybuf) =====
__global__ __launch_bounds__(256) void k_ssd_y(
    const float* __restrict__ hbc, const float* __restrict__ dtp,
    const float* __restrict__ cum, const float* __restrict__ sprev,
    const float* __restrict__ Dvec, float* __restrict__ ybuf, int l)
{
    __shared__ ushort_t Xt[64 * 136];
    __shared__ ushort_t BlsT[128 * 40];
    __shared__ ushort_t ClsT[128 * 40];
    __shared__ ushort_t Gls[128 * 136];
    __shared__ ushort_t Spt[64 * 40];
    __shared__ float cumls[QCH];
    __shared__ float dtls[QCH];
    const int bid = blockIdx.x;
    const int c = bid & (NC - 1);
    const int hh = (bid / NC) & (NH - 1);
    const int b = bid / (NC * NH);
    const int m0 = b * T_ + c * QCH;
    const int tid = threadIdx.x;

    if (tid < QCH) {
        cumls[tid] = cum[(m0 + tid) * NH + hh];
        dtls[tid] = dtp[(m0 + tid) * NH + hh];
    }
    {
        const int p = tid & 63;
        const int s0 = tid >> 6;
#pragma unroll
        for (int pass = 0; pass < 32; ++pass) {
            const int s = s0 + pass * 4;
            Xt[p * 136 + s] = f2b(hbc[(m0 + s) * CONVDIM + hh * 64 + p]);
        }
    }
    for (int e = tid; e < QCH * 16; e += 256) {
        const int n = e & 15, s = e >> 4;
        BlsT[s * 40 + n] = f2b(hbc[(m0 + s) * CONVDIM + DINNER + n]);
        BlsT[s * 40 + 16 + n] = 0;
        ClsT[s * 40 + n] = f2b(hbc[(m0 + s) * CONVDIM + DINNER + NSTATE + n]);
        ClsT[s * 40 + 16 + n] = 0;
    }
    for (int e = tid; e < 1024; e += 256) {
        const int n = e & 15, p = e >> 4;
        Spt[p * 40 + n] = f2b(sprev[bid * 1024 + p * 16 + n]);
        Spt[p * 40 + 16 + n] = 0;
    }
    __syncthreads();

    const int lane = tid & 63, w = tid >> 6;
    const int wrow = w * 32;
    const int r16 = lane & 15, q8 = (lane >> 4) * 8, q4 = (lane >> 4) * 4;
    const float Dh = Dvec[l * NH + hh];

    bf8 cfr[2];
#pragma unroll
    for (int i = 0; i < 2; ++i)
        cfr[i] = *(const bf8*)&ClsT[(wrow + i * 16 + r16) * 40 + q8];

    float cumt[8], et[8];
#pragma unroll
    for (int i = 0; i < 2; ++i)
#pragma unroll
        for (int r = 0; r < 4; ++r) {
            const int t = wrow + i * 16 + q4 + r;
            cumt[i * 4 + r] = cumls[t];
            et[i * 4 + r] = __expf(cumls[t]);
        }

    f4v acc[2][4];
#pragma unroll
    for (int j = 0; j < 4; ++j) {
        const bf8 sf = *(const bf8*)&Spt[(j * 16 + r16) * 40 + q8];
#pragma unroll
        for (int i = 0; i < 2; ++i) {
            f4v z = (f4v)0.f;
            z = __builtin_amdgcn_mfma_f32_16x16x32_bf16(cfr[i], sf, z, 0, 0, 0);
#pragma unroll
            for (int r = 0; r < 4; ++r) {
                const int t = wrow + i * 16 + q4 + r;
                const int p = j * 16 + r16;
                acc[i][j][r] = z[r] * et[i * 4 + r] + Dh * b2f(Xt[p * 136 + t]);
            }
        }
    }

#pragma unroll
    for (int ts = 0; ts < 8; ++ts) {
        const bf8 bf = *(const bf8*)&BlsT[(ts * 16 + r16) * 40 + q8];
        const int s = ts * 16 + r16;
        const float cs = cumls[s];
        const float ds = dtls[s];
#pragma unroll
        for (int i = 0; i < 2; ++i) {
            f4v g = (f4v)0.f;
            g = __builtin_amdgcn_mfma_f32_16x16x32_bf16(cfr[i], bf, g, 0, 0, 0);
#pragma unroll
            for (int r = 0; r < 4; ++r) {
                const int t = wrow + i * 16 + q4 + r;
                const float val = (s <= t) ? __expf(cumt[i * 4 + r] - cs) * ds * g[r] : 0.f;
                Gls[t * 136 + s] = f2b(val);
            }
        }
    }
    __syncthreads();

#pragma unroll
    for (int kc = 0; kc < 128; kc += 32) {
        bf8 af[2];
#pragma unroll
        for (int i = 0; i < 2; ++i)
            af[i] = *(const bf8*)&Gls[(wrow + i * 16 + r16) * 136 + kc + q8];
#pragma unroll
        for (int j = 0; j < 4; ++j) {
            const bf8 xf = *(const bf8*)&Xt[(j * 16 + r16) * 136 + kc + q8];
#pragma unroll
            for (int i = 0; i < 2; ++i)
                acc[i][j] = __builtin_amdgcn_mfma_f32_16x16x32_bf16(af[i], xf, acc[i][j], 0, 0, 0);
        }
    }

#pragma unroll
    for (int i = 0; i < 2; ++i)
#pragma unroll
        for (int r = 0; r < 4; ++r) {
            const int t = wrow + i * 16 + q4 + r;
#pragma unroll
            for (int j = 0; j < 4; ++j) {
                const int p = j * 16 + r16;
                ybuf[(m0 + t) * DINNER + hh * 64 + p] = acc[i][j][r];
            }
        }
}

// ===== final rmsnorm + partial mean-pool (proven) =====
__global__ __launch_bounds__(256) void k_finalnorm_pool(
    const float* __restrict__ h, const float* __restrict__ nfw,
    float* __restrict__ part)
{
    __shared__ float ht[2048];
    __shared__ float red[256];
    __shared__ float rstd[16];
    __shared__ float padd[256];
    const int tile = blockIdx.x & 127;
    const int b = blockIdx.x >> 7;
    const int m0 = b * T_ + tile * 16;
    const int tid = threadIdx.x;
    for (int e = tid; e < 2048; e += 256) ht[e] = h[m0 * DM + e];
    __syncthreads();
    {
        const int tg = tid >> 4, j0 = tid & 15;
        float p = 0.f;
#pragma unroll
        for (int k = 0; k < 8; ++k) { const float v = ht[tg * 128 + j0 + 16 * k]; p += v * v; }
        red[tid] = p;
    }
    __syncthreads();
    if (tid < 16) {
        float s = 0.f;
#pragma unroll
        for (int q = 0; q < 16; ++q) s += red[tid * 16 + q];
        rstd[tid] = rsqrtf(s * (1.f / 128.f) + EPSF);
    }
    __syncthreads();
    const int d = tid & 127, half = tid >> 7;
    float ps = 0.f;
#pragma unroll
    for (int i0 = 0; i0 < 8; ++i0) { const int i = half + 2 * i0; ps += ht[i * 128 + d] * rstd[i]; }
    padd[tid] = ps;
    __syncthreads();
    if (tid < 128) part[(b * 128 + tile) * 128 + tid] = (padd[tid] + padd[128 + tid]) * nfw[tid];
}

// ===== pooled reduce + head GEMM (proven) =====
__global__ __launch_bounds__(256) void k_head(
    const float* __restrict__ part, const float* __restrict__ ow,
    const float* __restrict__ ob, float* __restrict__ out)
{
    __shared__ float pooled[128];
    const int b = blockIdx.x;
    const int tid = threadIdx.x;
    if (tid < 128) {
        float s = 0.f;
        for (int tile = 0; tile < 128; ++tile) s += part[(b * 128 + tile) * 128 + tid];
        pooled[tid] = s * (1.f / (float)T_);
    }
    __syncthreads();
    for (int o = tid; o < DIMX; o += 256) {
        float acc = ob[o];
#pragma unroll 4
        for (int d = 0; d < 128; ++d) acc += pooled[d] * ow[d * DIMX + o];
        out[b * DIMX + o] = acc;
    }
}

extern "C" void kernel_launch(void* const* d_in, const int* in_sizes, int n_in,
                              void* d_out, int out_size, void* d_ws, size_t ws_size,
                              hipStream_t stream)
{
    const float* x         = (const float*)d_in[0];
    const float* in_w      = (const float*)d_in[1];
    const float* in_b      = (const float*)d_in[2];
    const float* norm_w    = (const float*)d_in[3];
    const float* inproj_w  = (const float*)d_in[4];
    const float* conv_w    = (const float*)d_in[5];
    const float* conv_b    = (const float*)d_in[6];
    const float* A_log     = (const float*)d_in[7];
    const float* Dvec      = (const float*)d_in[8];
    const float* dt_bias   = (const float*)d_in[9];
    const float* gnorm_w   = (const float*)d_in[10];
    const float* outproj_w = (const float*)d_in[11];
    const float* normf_w   = (const float*)d_in[12];
    const float* out_w     = (const float*)d_in[13];
    const float* out_b     = (const float*)d_in[14];

    float* ws    = (float*)d_ws;
    float* h     = ws + OFF_H;
    float* proj  = ws + OFF_PROJ;
    float* hbc   = ws + OFF_HBC;
    float* ybuf  = ws + OFF_Y;
    float* dtp   = ws + OFF_DTP;
    float* cumb  = ws + OFF_CUM;
    float* zbuf  = ws + OFF_Z;
    float* sprev = ws + OFF_SPREV;
    float* dec   = ws + OFF_DEC;
    float* part  = ws + OFF_PART;
    ushort_t* bf_scr = (ushort_t*)(ws + OFF_BF);
    ushort_t* wt_in  = (ushort_t*)(ws + OFF_WTIN);
    ushort_t* wt_inp = (ushort_t*)(ws + OFF_WTINP);
    ushort_t* wt_out = (ushort_t*)(ws + OFF_WTOUT);

    k_wt_all<<<68, 256, 0, stream>>>(in_w, inproj_w, outproj_w, wt_in, wt_inp, wt_out);

    k_gemm<512, 128, 0, 1, false><<<dim3(MTOK / 64, 2), 256, 0, stream>>>(x, wt_in, in_b, h);

    for (int l = 0; l < LLAYERS; ++l) {
        k_rmsnorm<<<MTOK / 4, 256, 0, stream>>>(h, norm_w + l * DM, bf_scr);
        k_gemm<128, PROJ, PROJ, 0, true><<<dim3(MTOK / 64, 9), 256, 0, stream>>>(
            bf_scr, wt_inp + l * 576 * 128, nullptr, proj);
        k_convdt<<<(MTOK * CONVDIM) / 256 + B_ * NH * NC, 256, 0, stream>>>(
            proj, conv_w, conv_b, A_log, dt_bias, hbc, dtp, cumb, l);
        k_ssd_state<<<B_ * NH * NC, 256, 0, stream>>>(hbc, dtp, cumb, zbuf, dec);
        k_state_scan<<<B_ * NH, 256, 0, stream>>>(zbuf, dec, sprev);
        k_ssd_y<<<B_ * NH * NC, 256, 0, stream>>>(hbc, dtp, cumb, sprev, Dvec, ybuf, l);
        k_gnorm<<<MTOK / 4, 256, 0, stream>>>(ybuf, proj, gnorm_w + l * DINNER, bf_scr);
        k_gemm<256, 128, 0, 2, true><<<dim3(MTOK / 64, 2), 256, 0, stream>>>(
            bf_scr, wt_out + l * 128 * 256, nullptr, h);
    }

    k_finalnorm_pool<<<B_ * (T_ / 16), 256, 0, stream>>>(h, normf_w, part);
    k_head<<<B_, 256, 0, stream>>>(part, out_w, out_b, (float*)d_out);
}